// Round 1
// baseline (713.411 us; speedup 1.0000x reference)
//
#include <hip/hip_runtime.h>
#include <math.h>

// PrimitiveTokenizer: N=4096 rows x S=64 slots, D=256.
// Pipeline:
//   K3 window_kernel: per-block = 1024 slots = 16 rows.
//     - stage values/kinds/mask in LDS
//     - deterministic ballot-compaction of masked slots grouped by kind (K=8)
//     - per kind, chunks of 64 slots: Fourier feats -> hidden(gelu) -> out = hid @ w2[k]
//     - block-local masked-mean pooling (no atomics, deterministic) -> h_num[N,256] in ws
//   K4 fuse_kernel: h = [h_num | type_emb | layer_emb] -> gelu(h@W1+b1)@W2+b2 + meta@Mw+Mb
// All fp32 (reference is fp32; no fp32 MFMA on CDNA4 -> vector FMA).

#define S_      64
#define D_      256
#define BF_     24
#define FF_     48
#define KK_     8
#define WIN_    1024
#define RPW_    16
#define NWIN_   256

__device__ __forceinline__ float gelu_exact(float x) {
    return 0.5f * x * (1.0f + erff(x * 0.70710678118654752f));
}

__global__ __launch_bounds__(512) void window_kernel(
    const float* __restrict__ values, const int* __restrict__ kinds,
    const int* __restrict__ mask, const float* __restrict__ B_ff,
    const float* __restrict__ kind_emb, const float* __restrict__ w1,
    const float* __restrict__ b1, const float* __restrict__ w2,
    const float* __restrict__ b2, float* __restrict__ h_num)
{
    __shared__ float vals[WIN_];                 // 4 KB
    __shared__ unsigned char knd[WIN_];          // 1 KB
    __shared__ unsigned char msk[WIN_];          // 1 KB
    __shared__ unsigned short list[WIN_];        // 2 KB (positions grouped by kind, deterministic order)
    __shared__ int cnt_s[KK_], off_s[KK_];
    __shared__ float denom_inv[RPW_];
    __shared__ float twopiB[BF_];
    __shared__ float row_acc[RPW_][D_];          // 16 KB
    __shared__ float ff_s[64][FF_];              // 12 KB
    __shared__ float hid[64][D_];                // 64 KB (reused: hidden, then out staging)

    const int t = threadIdx.x;
    const int w = blockIdx.x;
    const int base = w * WIN_;

    for (int i = t; i < WIN_; i += 512) {
        vals[i] = values[base + i];
        knd[i]  = (unsigned char)kinds[base + i];
        msk[i]  = (unsigned char)mask[base + i];
    }
    if (t < BF_) twopiB[t] = 6.283185307179586f * B_ff[t];
    for (int i = t; i < RPW_ * D_; i += 512) ((float*)row_acc)[i] = 0.0f;
    __syncthreads();

    if (t < RPW_) {
        int c = 0;
        for (int s = 0; s < S_; ++s) c += msk[t * S_ + s];
        denom_inv[t] = 1.0f / (float)(c > 0 ? c : 1);
    }

    // deterministic per-kind compaction by wave 0
    if (t < 64) {
        int cnts[KK_];
        #pragma unroll
        for (int k = 0; k < KK_; ++k) cnts[k] = 0;
        for (int c = 0; c < WIN_ / 64; ++c) {
            int p = c * 64 + t;
            int kd = knd[p]; int mk = msk[p];
            #pragma unroll
            for (int k = 0; k < KK_; ++k) {
                unsigned long long bal = __ballot(mk && (kd == k));
                cnts[k] += __popcll(bal);
            }
        }
        int offk[KK_]; int run = 0;
        #pragma unroll
        for (int k = 0; k < KK_; ++k) { offk[k] = run; run += cnts[k]; }
        if (t == 0) {
            #pragma unroll
            for (int k = 0; k < KK_; ++k) { cnt_s[k] = cnts[k]; off_s[k] = offk[k]; }
        }
        int fillk[KK_];
        #pragma unroll
        for (int k = 0; k < KK_; ++k) fillk[k] = 0;
        const unsigned long long below = (1ull << t) - 1ull;
        for (int c = 0; c < WIN_ / 64; ++c) {
            int p = c * 64 + t;
            int kd = knd[p]; int mk = msk[p];
            #pragma unroll
            for (int k = 0; k < KK_; ++k) {
                unsigned long long bal = __ballot(mk && (kd == k));
                if (mk && (kd == k)) {
                    int rank = __popcll(bal & below);
                    list[offk[k] + fillk[k] + rank] = (unsigned short)p;
                }
                fillk[k] += __popcll(bal);
            }
        }
    }
    __syncthreads();

    const int d  = t & (D_ - 1);       // phase B: owned output dim
    const int td = t & 63, ts = t >> 6;
    const int d0 = td * 4, s0 = ts * 8; // phase C: 8 slots x 4 dims per thread

    for (int k = 0; k < KK_; ++k) {
        const int len = cnt_s[k];
        const int off = off_s[k];
        float w1r[FF_];
        #pragma unroll
        for (int j = 0; j < FF_; ++j) w1r[j] = w1[(k * FF_ + j) * D_ + d];
        const float b1r = b1[k * D_ + d];
        const float ke  = kind_emb[k * D_ + d];
        const float4 b2v = *(const float4*)&b2[k * D_ + d0];
        const float* w2k = w2 + k * D_ * D_;
        const int nch = (len + 63) >> 6;

        for (int c = 0; c < nch; ++c) {
            const int L = min(64, len - c * 64);
            __syncthreads();  // prev chunk's accumulate readers done before overwrite
            // Fourier features for this chunk
            for (int i = t; i < L * FF_; i += 512) {
                int ss = i / FF_, j = i - ss * FF_;
                float v = vals[list[off + c * 64 + ss]];
                int jm = (j < BF_) ? j : j - BF_;
                float y = v * twopiB[jm];
                ff_s[ss][j] = (j < BF_) ? sinf(y) : cosf(y);
            }
            __syncthreads();
            // hidden = gelu(ff @ w1[k] + b1[k])
            {
                int sh = (t >> 8) * 32;
                for (int ss = sh; ss < sh + 32; ++ss) {
                    if (ss >= L) { hid[ss][d] = 0.0f; continue; }
                    float acc = b1r;
                    const float4* fp = (const float4*)ff_s[ss];
                    #pragma unroll
                    for (int jj = 0; jj < FF_ / 4; ++jj) {
                        float4 f = fp[jj];
                        acc += f.x * w1r[jj * 4 + 0];
                        acc += f.y * w1r[jj * 4 + 1];
                        acc += f.z * w1r[jj * 4 + 2];
                        acc += f.w * w1r[jj * 4 + 3];
                    }
                    hid[ss][d] = gelu_exact(acc);
                }
            }
            __syncthreads();
            // out = hid @ w2[k] : 8 slots x 4 dims per thread
            float o[8][4];
            #pragma unroll
            for (int i = 0; i < 8; ++i) {
                #pragma unroll
                for (int q = 0; q < 4; ++q) o[i][q] = 0.0f;
            }
            for (int e = 0; e < D_; e += 4) {
                float4 wr0 = *(const float4*)&w2k[(e + 0) * D_ + d0];
                float4 wr1 = *(const float4*)&w2k[(e + 1) * D_ + d0];
                float4 wr2 = *(const float4*)&w2k[(e + 2) * D_ + d0];
                float4 wr3 = *(const float4*)&w2k[(e + 3) * D_ + d0];
                #pragma unroll
                for (int i = 0; i < 8; ++i) {
                    float4 h4 = *(const float4*)&hid[s0 + i][e];
                    o[i][0] += h4.x * wr0.x + h4.y * wr1.x + h4.z * wr2.x + h4.w * wr3.x;
                    o[i][1] += h4.x * wr0.y + h4.y * wr1.y + h4.z * wr2.y + h4.w * wr3.y;
                    o[i][2] += h4.x * wr0.z + h4.y * wr1.z + h4.z * wr2.z + h4.w * wr3.z;
                    o[i][3] += h4.x * wr0.w + h4.y * wr1.w + h4.z * wr2.w + h4.w * wr3.w;
                }
            }
            __syncthreads();  // all GEMM reads of hid done
            #pragma unroll
            for (int i = 0; i < 8; ++i) {
                float4 v4;
                v4.x = o[i][0] + b2v.x;
                v4.y = o[i][1] + b2v.y;
                v4.z = o[i][2] + b2v.z;
                v4.w = o[i][3] + b2v.w;
                *(float4*)&hid[s0 + i][d0] = v4;  // restage out over hid
            }
            __syncthreads();
            // deterministic block-local pooling accumulate
            if (t < D_) {
                for (int ss = 0; ss < L; ++ss) {
                    int p = list[off + c * 64 + ss];
                    int r = p >> 6;
                    row_acc[r][t] += hid[ss][t] + ke;
                }
            }
        }
    }
    __syncthreads();
    for (int i = t; i < RPW_ * D_; i += 512) {
        int r = i >> 8;
        h_num[(w * RPW_ + r) * D_ + (i & (D_ - 1))] = ((float*)row_acc)[i] * denom_inv[r];
    }
}

__global__ __launch_bounds__(256) void fuse_kernel(
    const float* __restrict__ h_num, const int* __restrict__ pt,
    const int* __restrict__ lid, const float* __restrict__ meta,
    const float* __restrict__ type_emb, const float* __restrict__ layer_emb,
    const float* __restrict__ fw1, const float* __restrict__ fb1,
    const float* __restrict__ fw2, const float* __restrict__ fb2,
    const float* __restrict__ meta_w, const float* __restrict__ meta_b,
    float* __restrict__ out)
{
    __shared__ float hb[8][768];      // 24 KB; later aliased for z (8x256)
    __shared__ float meta_s[8][4];
    const int t = threadIdx.x;
    const int rb = blockIdx.x * 8;

    for (int i = t; i < 8 * 768; i += 256) {
        int r = i / 768, j = i - r * 768;
        int n = rb + r;
        float v;
        if (j < 256)       v = h_num[n * 256 + j];
        else if (j < 512)  v = type_emb[pt[n] * 256 + (j - 256)];
        else               v = layer_emb[lid[n] * 256 + (j - 512)];
        hb[r][j] = v;
    }
    if (t < 32) meta_s[t >> 2][t & 3] = meta[(rb + (t >> 2)) * 4 + (t & 3)];
    __syncthreads();

    const int d0 = (t & 63) * 4;
    const int tr = t >> 6;            // rows tr*2, tr*2+1

    float a[2][4];
    #pragma unroll
    for (int rr = 0; rr < 2; ++rr) { a[rr][0] = a[rr][1] = a[rr][2] = a[rr][3] = 0.0f; }
    for (int j = 0; j < 768; j += 4) {
        float4 q0 = *(const float4*)&fw1[(j + 0) * 256 + d0];
        float4 q1 = *(const float4*)&fw1[(j + 1) * 256 + d0];
        float4 q2 = *(const float4*)&fw1[(j + 2) * 256 + d0];
        float4 q3 = *(const float4*)&fw1[(j + 3) * 256 + d0];
        #pragma unroll
        for (int rr = 0; rr < 2; ++rr) {
            float4 h4 = *(const float4*)&hb[tr * 2 + rr][j];
            a[rr][0] += h4.x * q0.x + h4.y * q1.x + h4.z * q2.x + h4.w * q3.x;
            a[rr][1] += h4.x * q0.y + h4.y * q1.y + h4.z * q2.y + h4.w * q3.y;
            a[rr][2] += h4.x * q0.z + h4.y * q1.z + h4.z * q2.z + h4.w * q3.z;
            a[rr][3] += h4.x * q0.w + h4.y * q1.w + h4.z * q2.w + h4.w * q3.w;
        }
    }
    __syncthreads();                   // all reads of hb done
    float* zb = &hb[0][0];             // alias: z[8][256]
    {
        float4 bv = *(const float4*)&fb1[d0];
        #pragma unroll
        for (int rr = 0; rr < 2; ++rr) {
            float4 z4;
            z4.x = gelu_exact(a[rr][0] + bv.x);
            z4.y = gelu_exact(a[rr][1] + bv.y);
            z4.z = gelu_exact(a[rr][2] + bv.z);
            z4.w = gelu_exact(a[rr][3] + bv.w);
            *(float4*)&zb[(tr * 2 + rr) * 256 + d0] = z4;
        }
    }
    __syncthreads();

    float a2[2][4];
    #pragma unroll
    for (int rr = 0; rr < 2; ++rr) { a2[rr][0] = a2[rr][1] = a2[rr][2] = a2[rr][3] = 0.0f; }
    for (int e = 0; e < 256; e += 4) {
        float4 q0 = *(const float4*)&fw2[(e + 0) * 256 + d0];
        float4 q1 = *(const float4*)&fw2[(e + 1) * 256 + d0];
        float4 q2 = *(const float4*)&fw2[(e + 2) * 256 + d0];
        float4 q3 = *(const float4*)&fw2[(e + 3) * 256 + d0];
        #pragma unroll
        for (int rr = 0; rr < 2; ++rr) {
            float4 z4 = *(const float4*)&zb[(tr * 2 + rr) * 256 + e];
            a2[rr][0] += z4.x * q0.x + z4.y * q1.x + z4.z * q2.x + z4.w * q3.x;
            a2[rr][1] += z4.x * q0.y + z4.y * q1.y + z4.z * q2.y + z4.w * q3.y;
            a2[rr][2] += z4.x * q0.z + z4.y * q1.z + z4.z * q2.z + z4.w * q3.z;
            a2[rr][3] += z4.x * q0.w + z4.y * q1.w + z4.z * q2.w + z4.w * q3.w;
        }
    }

    float4 b2v = *(const float4*)&fb2[d0];
    float4 mbv = *(const float4*)&meta_b[d0];
    float4 m0v = *(const float4*)&meta_w[0 * 256 + d0];
    float4 m1v = *(const float4*)&meta_w[1 * 256 + d0];
    float4 m2v = *(const float4*)&meta_w[2 * 256 + d0];
    float4 m3v = *(const float4*)&meta_w[3 * 256 + d0];
    #pragma unroll
    for (int rr = 0; rr < 2; ++rr) {
        int r = tr * 2 + rr;
        int n = rb + r;
        float m0 = meta_s[r][0], m1 = meta_s[r][1], m2 = meta_s[r][2], m3 = meta_s[r][3];
        float4 res;
        res.x = a2[rr][0] + b2v.x + mbv.x + m0 * m0v.x + m1 * m1v.x + m2 * m2v.x + m3 * m3v.x;
        res.y = a2[rr][1] + b2v.y + mbv.y + m0 * m0v.y + m1 * m1v.y + m2 * m2v.y + m3 * m3v.y;
        res.z = a2[rr][2] + b2v.z + mbv.z + m0 * m0v.z + m1 * m1v.z + m2 * m2v.z + m3 * m3v.z;
        res.w = a2[rr][3] + b2v.w + mbv.w + m0 * m0v.w + m1 * m1v.w + m2 * m2v.w + m3 * m3v.w;
        *(float4*)&out[n * 256 + d0] = res;
    }
}

extern "C" void kernel_launch(void* const* d_in, const int* in_sizes, int n_in,
                              void* d_out, int out_size, void* d_ws, size_t ws_size,
                              hipStream_t stream) {
    const float* values    = (const float*)d_in[0];
    const int*   kinds     = (const int*)d_in[1];
    const int*   mask      = (const int*)d_in[2];
    const int*   prim_type = (const int*)d_in[3];
    const int*   layer_id  = (const int*)d_in[4];
    const float* meta      = (const float*)d_in[5];
    const float* B_ff      = (const float*)d_in[6];
    const float* kind_emb  = (const float*)d_in[7];
    const float* type_emb  = (const float*)d_in[8];
    const float* layer_emb = (const float*)d_in[9];
    const float* mlp_w1    = (const float*)d_in[10];
    const float* mlp_b1    = (const float*)d_in[11];
    const float* mlp_w2    = (const float*)d_in[12];
    const float* mlp_b2    = (const float*)d_in[13];
    const float* fuse_w1   = (const float*)d_in[14];
    const float* fuse_b1   = (const float*)d_in[15];
    const float* fuse_w2   = (const float*)d_in[16];
    const float* fuse_b2   = (const float*)d_in[17];
    const float* meta_w    = (const float*)d_in[18];
    const float* meta_b    = (const float*)d_in[19];

    float* h_num = (float*)d_ws;   // 4096*256 f32 = 4 MB
    float* out   = (float*)d_out;

    window_kernel<<<NWIN_, 512, 0, stream>>>(values, kinds, mask, B_ff, kind_emb,
                                             mlp_w1, mlp_b1, mlp_w2, mlp_b2, h_num);
    fuse_kernel<<<512, 256, 0, stream>>>(h_num, prim_type, layer_id, meta,
                                         type_emb, layer_emb, fuse_w1, fuse_b1,
                                         fuse_w2, fuse_b2, meta_w, meta_b, out);
}

// Round 2
// 311.955 us; speedup vs baseline: 2.2869x; 2.2869x over previous
//
#include <hip/hip_runtime.h>
#include <math.h>

// PrimitiveTokenizer, round 2: MFMA (bf16 hi/lo split, 3-MFMA per tile) for both
// per-kind MLP GEMMs inside the window kernel. Weights pre-converted once per
// launch into B-fragment-layout hi/lo planes in d_ws.
//
// ws layout (shorts for frags, then h_num f32):
//   w2f_hi: 8 kind x 8 kstep x 16 nt frags x (64 lane x 8 bf16)  = 524288 shorts (1 MB)
//   w2f_lo: +524288
//   w1f_hi: 8 kind x 2 kstep x 16 nt x 512                        = 131072 shorts
//   w1f_lo: +131072
//   h_num : f32[4096][256] at byte offset 2,621,440 (4 MB)
// total ws: 6.5 MB

#define S_      64
#define D_      256
#define BF_     24
#define FF_     48
#define KK_     8
#define WIN_    1024
#define RPW_    16
#define NWIN_   256

#define FFS     72      // ff lds stride (shorts): 16B aligned, conflict-free
#define HS      264     // hid lds stride (shorts): 16B aligned, conflict-free
#define OS      257     // outst lds stride (floats)

#define W2F_LO  524288
#define W1F_HI  1048576
#define W1F_LO  1179648
#define HNUM_OFF 2621440

typedef __attribute__((ext_vector_type(8))) short frag;
typedef __attribute__((ext_vector_type(4))) float f32x4;

__device__ __forceinline__ float gelu_exact(float x) {
    return 0.5f * x * (1.0f + erff(x * 0.70710678118654752f));
}

__device__ __forceinline__ unsigned short f2bf_rn(float x) {
    unsigned int u = __float_as_uint(x);
    unsigned int r = (u + 0x7fffu + ((u >> 16) & 1u)) >> 16;
    return (unsigned short)r;
}
__device__ __forceinline__ float bf2f(unsigned short h) {
    return __uint_as_float(((unsigned int)h) << 16);
}
__device__ __forceinline__ void split_bf(float x, unsigned short& h, unsigned short& l) {
    unsigned short hh = f2bf_rn(x);
    h = hh;
    l = f2bf_rn(x - bf2f(hh));
}

// ---------------- prep: weights -> bf16 hi/lo fragment planes ----------------
__global__ __launch_bounds__(512) void prep_kernel(
    const float* __restrict__ w1, const float* __restrict__ w2,
    short* __restrict__ ws)
{
    int tid = blockIdx.x * 512 + threadIdx.x;
    int fid = tid >> 6, ln = tid & 63;
    int lr = ln & 15, kq = ln >> 4;
    if (fid >= 1280) return;
    union U { unsigned short u[8]; frag f; } hu, lu;
    if (fid < 1024) {
        int kind = fid >> 7, kst = (fid >> 4) & 7, nt = fid & 15;
        int col = nt * 16 + lr;
        #pragma unroll
        for (int b = 0; b < 8; ++b) {
            int k = kst * 32 + kq * 8 + b;
            float x = w2[(kind * 256 + k) * 256 + col];
            split_bf(x, hu.u[b], lu.u[b]);
        }
        int dst = fid * 512 + ln * 8;
        *(frag*)(ws + dst) = hu.f;
        *(frag*)(ws + W2F_LO + dst) = lu.f;
    } else {
        int f2 = fid - 1024;
        int kind = f2 >> 5, kst = (f2 >> 4) & 1, nt = f2 & 15;
        int col = nt * 16 + lr;
        #pragma unroll
        for (int b = 0; b < 8; ++b) {
            int k = kst * 32 + kq * 8 + b;
            float x = (k < FF_) ? w1[(kind * FF_ + k) * 256 + col] : 0.0f;
            split_bf(x, hu.u[b], lu.u[b]);
        }
        int dst = f2 * 512 + ln * 8;
        *(frag*)(ws + W1F_HI + dst) = hu.f;
        *(frag*)(ws + W1F_LO + dst) = lu.f;
    }
}

// ---------------- window kernel ----------------
__global__ __launch_bounds__(512) void window_kernel(
    const float* __restrict__ values, const int* __restrict__ kinds,
    const int* __restrict__ mask, const float* __restrict__ B_ff,
    const float* __restrict__ kind_emb,
    const float* __restrict__ b1, const float* __restrict__ b2,
    const short* __restrict__ wsf, float* __restrict__ h_num)
{
    __shared__ float vals[WIN_];
    __shared__ unsigned char knd[WIN_];
    __shared__ unsigned char msk[WIN_];
    __shared__ unsigned short list[WIN_];
    __shared__ int cnt_s[KK_], off_s[KK_];
    __shared__ float denom_inv[RPW_];
    __shared__ float twopiB[BF_];
    __shared__ float row_acc0[RPW_ * D_];
    __shared__ float row_acc1[RPW_ * D_];
    __shared__ short ffh[64 * FFS];
    __shared__ short ffl[64 * FFS];
    __shared__ __align__(16) char hid_u[64 * HS * 2 * 2];   // hid_hi|hid_lo, aliased by outst

    short* hid_hi = (short*)hid_u;
    short* hid_lo = (short*)(hid_u + 64 * HS * 2);
    float* outst  = (float*)hid_u;

    const short* w2f_hi = wsf;
    const short* w2f_lo = wsf + W2F_LO;
    const short* w1f_hi = wsf + W1F_HI;
    const short* w1f_lo = wsf + W1F_LO;

    const int t = threadIdx.x;
    const int w = blockIdx.x;
    const int base = w * WIN_;
    const int wv = t >> 6, ln = t & 63, lr = ln & 15, kq = ln >> 4;

    for (int i = t; i < WIN_; i += 512) {
        vals[i] = values[base + i];
        knd[i]  = (unsigned char)kinds[base + i];
        msk[i]  = (unsigned char)mask[base + i];
    }
    if (t < BF_) twopiB[t] = 6.283185307179586f * B_ff[t];
    for (int i = t; i < RPW_ * D_; i += 512) { row_acc0[i] = 0.0f; row_acc1[i] = 0.0f; }
    // zero ff k-padding (cols 48..63), all 64 rows, both planes
    for (int i = t; i < 64 * 16; i += 512) {
        int r = i >> 4, cp = FF_ + (i & 15);
        ffh[r * FFS + cp] = 0; ffl[r * FFS + cp] = 0;
    }
    __syncthreads();

    if (t < RPW_) {
        int c = 0;
        for (int s = 0; s < S_; ++s) c += msk[t * S_ + s];
        denom_inv[t] = 1.0f / (float)(c > 0 ? c : 1);
    }

    // deterministic per-kind compaction by wave 0
    if (t < 64) {
        int cnts[KK_];
        #pragma unroll
        for (int k = 0; k < KK_; ++k) cnts[k] = 0;
        for (int c = 0; c < WIN_ / 64; ++c) {
            int p = c * 64 + t;
            int kd = knd[p]; int mk = msk[p];
            #pragma unroll
            for (int k = 0; k < KK_; ++k) {
                unsigned long long bal = __ballot(mk && (kd == k));
                cnts[k] += __popcll(bal);
            }
        }
        int offk[KK_]; int run = 0;
        #pragma unroll
        for (int k = 0; k < KK_; ++k) { offk[k] = run; run += cnts[k]; }
        if (t == 0) {
            #pragma unroll
            for (int k = 0; k < KK_; ++k) { cnt_s[k] = cnts[k]; off_s[k] = offk[k]; }
        }
        int fillk[KK_];
        #pragma unroll
        for (int k = 0; k < KK_; ++k) fillk[k] = 0;
        const unsigned long long below = (1ull << t) - 1ull;
        for (int c = 0; c < WIN_ / 64; ++c) {
            int p = c * 64 + t;
            int kd = knd[p]; int mk = msk[p];
            #pragma unroll
            for (int k = 0; k < KK_; ++k) {
                unsigned long long bal = __ballot(mk && (kd == k));
                if (mk && (kd == k)) {
                    int rank = __popcll(bal & below);
                    list[offk[k] + fillk[k] + rank] = (unsigned short)p;
                }
                fillk[k] += __popcll(bal);
            }
        }
    }
    __syncthreads();

    const int pcol = t & 255, ph = t >> 8;
    float* racc = ph ? row_acc1 : row_acc0;

    for (int k8 = 0; k8 < KK_; ++k8) {
        const int len = cnt_s[k8];
        const int off = off_s[k8];
        const int nch = (len + 63) >> 6;
        const float ke = kind_emb[k8 * 256 + pcol];

        for (int c = 0; c < nch; ++c) {
            const int L = min(64, len - c * 64);
            const int c64 = c * 64;

            // ---- Fourier features (bf16 hi/lo) ----
            for (int i = t; i < L * FF_; i += 512) {
                int ss = i / FF_, j = i - ss * FF_;
                float v = vals[list[off + c64 + ss]];
                int jm = (j < BF_) ? j : j - BF_;
                float y = v * twopiB[jm];
                float sv = (j < BF_) ? sinf(y) : cosf(y);
                unsigned short h, l;
                split_bf(sv, h, l);
                ffh[ss * FFS + j] = (short)h;
                ffl[ss * FFS + j] = (short)l;
            }
            __syncthreads();

            // ---- GEMM1: hidden = gelu(ff @ w1 + b1), MFMA bf16x3 ----
            {
                f32x4 acc1[4][2];
                #pragma unroll
                for (int mt = 0; mt < 4; ++mt)
                    #pragma unroll
                    for (int n = 0; n < 2; ++n)
                        acc1[mt][n] = (f32x4)0.0f;

                #pragma unroll
                for (int kst = 0; kst < 2; ++kst) {
                    frag ah[4], al[4];
                    #pragma unroll
                    for (int mt = 0; mt < 4; ++mt) {
                        int ro = (mt * 16 + lr) * FFS + kst * 32 + kq * 8;
                        ah[mt] = *(const frag*)&ffh[ro];
                        al[mt] = *(const frag*)&ffl[ro];
                    }
                    #pragma unroll
                    for (int n = 0; n < 2; ++n) {
                        int fi = (k8 * 2 + kst) * 16 + (wv * 2 + n);
                        frag bh = *(const frag*)(w1f_hi + fi * 512 + ln * 8);
                        frag bl = *(const frag*)(w1f_lo + fi * 512 + ln * 8);
                        #pragma unroll
                        for (int mt = 0; mt < 4; ++mt) {
                            acc1[mt][n] = __builtin_amdgcn_mfma_f32_16x16x32_bf16(ah[mt], bh, acc1[mt][n], 0, 0, 0);
                            acc1[mt][n] = __builtin_amdgcn_mfma_f32_16x16x32_bf16(al[mt], bh, acc1[mt][n], 0, 0, 0);
                            acc1[mt][n] = __builtin_amdgcn_mfma_f32_16x16x32_bf16(ah[mt], bl, acc1[mt][n], 0, 0, 0);
                        }
                    }
                }
                // bias + gelu + split -> hid
                #pragma unroll
                for (int n = 0; n < 2; ++n) {
                    int col = (wv * 2 + n) * 16 + lr;
                    float b1v = b1[k8 * 256 + col];
                    #pragma unroll
                    for (int mt = 0; mt < 4; ++mt) {
                        #pragma unroll
                        for (int r = 0; r < 4; ++r) {
                            float g = gelu_exact(acc1[mt][n][r] + b1v);
                            unsigned short hh, ll;
                            split_bf(g, hh, ll);
                            int row = mt * 16 + kq * 4 + r;
                            hid_hi[row * HS + col] = (short)hh;
                            hid_lo[row * HS + col] = (short)ll;
                        }
                    }
                }
            }
            __syncthreads();

            // ---- GEMM2: out = hid @ w2 + b2, MFMA bf16x3 ----
            f32x4 acc2[4][2];
            #pragma unroll
            for (int mt = 0; mt < 4; ++mt)
                #pragma unroll
                for (int n = 0; n < 2; ++n)
                    acc2[mt][n] = (f32x4)0.0f;

            #pragma unroll 2
            for (int kst = 0; kst < 8; ++kst) {
                frag ah[4], al[4];
                #pragma unroll
                for (int mt = 0; mt < 4; ++mt) {
                    int ro = (mt * 16 + lr) * HS + kst * 32 + kq * 8;
                    ah[mt] = *(const frag*)&hid_hi[ro];
                    al[mt] = *(const frag*)&hid_lo[ro];
                }
                #pragma unroll
                for (int n = 0; n < 2; ++n) {
                    int fi = (k8 * 8 + kst) * 16 + (wv * 2 + n);
                    frag bh = *(const frag*)(w2f_hi + fi * 512 + ln * 8);
                    frag bl = *(const frag*)(w2f_lo + fi * 512 + ln * 8);
                    #pragma unroll
                    for (int mt = 0; mt < 4; ++mt) {
                        acc2[mt][n] = __builtin_amdgcn_mfma_f32_16x16x32_bf16(ah[mt], bh, acc2[mt][n], 0, 0, 0);
                        acc2[mt][n] = __builtin_amdgcn_mfma_f32_16x16x32_bf16(al[mt], bh, acc2[mt][n], 0, 0, 0);
                        acc2[mt][n] = __builtin_amdgcn_mfma_f32_16x16x32_bf16(ah[mt], bl, acc2[mt][n], 0, 0, 0);
                    }
                }
            }
            __syncthreads();   // all hid reads done; safe to alias with outst

            // ---- epilogue: outst = acc2 + b2 ----
            #pragma unroll
            for (int n = 0; n < 2; ++n) {
                int col = (wv * 2 + n) * 16 + lr;
                float b2v = b2[k8 * 256 + col];
                #pragma unroll
                for (int mt = 0; mt < 4; ++mt) {
                    #pragma unroll
                    for (int r = 0; r < 4; ++r) {
                        int row = mt * 16 + kq * 4 + r;
                        outst[row * OS + col] = acc2[mt][n][r] + b2v;
                    }
                }
            }
            __syncthreads();

            // ---- deterministic pooling (2 slot-halves) ----
            for (int ss = ph; ss < L; ss += 2) {
                int p = list[off + c64 + ss];
                racc[(p >> 6) * 256 + pcol] += outst[ss * OS + pcol] + ke;
            }
            __syncthreads();
        }
    }

    for (int i = t; i < RPW_ * D_; i += 512) {
        int r = i >> 8;
        h_num[(w * RPW_ + r) * D_ + (i & 255)] = (row_acc0[i] + row_acc1[i]) * denom_inv[r];
    }
}

// ---------------- fuse kernel (unchanged fp32 vector) ----------------
__global__ __launch_bounds__(256) void fuse_kernel(
    const float* __restrict__ h_num, const int* __restrict__ pt,
    const int* __restrict__ lid, const float* __restrict__ meta,
    const float* __restrict__ type_emb, const float* __restrict__ layer_emb,
    const float* __restrict__ fw1, const float* __restrict__ fb1,
    const float* __restrict__ fw2, const float* __restrict__ fb2,
    const float* __restrict__ meta_w, const float* __restrict__ meta_b,
    float* __restrict__ out)
{
    __shared__ float hb[8][768];
    __shared__ float meta_s[8][4];
    const int t = threadIdx.x;
    const int rb = blockIdx.x * 8;

    for (int i = t; i < 8 * 768; i += 256) {
        int r = i / 768, j = i - r * 768;
        int n = rb + r;
        float v;
        if (j < 256)       v = h_num[n * 256 + j];
        else if (j < 512)  v = type_emb[pt[n] * 256 + (j - 256)];
        else               v = layer_emb[lid[n] * 256 + (j - 512)];
        hb[r][j] = v;
    }
    if (t < 32) meta_s[t >> 2][t & 3] = meta[(rb + (t >> 2)) * 4 + (t & 3)];
    __syncthreads();

    const int d0 = (t & 63) * 4;
    const int tr = t >> 6;

    float a[2][4];
    #pragma unroll
    for (int rr = 0; rr < 2; ++rr) { a[rr][0] = a[rr][1] = a[rr][2] = a[rr][3] = 0.0f; }
    for (int j = 0; j < 768; j += 4) {
        float4 q0 = *(const float4*)&fw1[(j + 0) * 256 + d0];
        float4 q1 = *(const float4*)&fw1[(j + 1) * 256 + d0];
        float4 q2 = *(const float4*)&fw1[(j + 2) * 256 + d0];
        float4 q3 = *(const float4*)&fw1[(j + 3) * 256 + d0];
        #pragma unroll
        for (int rr = 0; rr < 2; ++rr) {
            float4 h4 = *(const float4*)&hb[tr * 2 + rr][j];
            a[rr][0] += h4.x * q0.x + h4.y * q1.x + h4.z * q2.x + h4.w * q3.x;
            a[rr][1] += h4.x * q0.y + h4.y * q1.y + h4.z * q2.y + h4.w * q3.y;
            a[rr][2] += h4.x * q0.z + h4.y * q1.z + h4.z * q2.z + h4.w * q3.z;
            a[rr][3] += h4.x * q0.w + h4.y * q1.w + h4.z * q2.w + h4.w * q3.w;
        }
    }
    __syncthreads();
    float* zb = &hb[0][0];
    {
        float4 bv = *(const float4*)&fb1[d0];
        #pragma unroll
        for (int rr = 0; rr < 2; ++rr) {
            float4 z4;
            z4.x = gelu_exact(a[rr][0] + bv.x);
            z4.y = gelu_exact(a[rr][1] + bv.y);
            z4.z = gelu_exact(a[rr][2] + bv.z);
            z4.w = gelu_exact(a[rr][3] + bv.w);
            *(float4*)&zb[(tr * 2 + rr) * 256 + d0] = z4;
        }
    }
    __syncthreads();

    float a2[2][4];
    #pragma unroll
    for (int rr = 0; rr < 2; ++rr) { a2[rr][0] = a2[rr][1] = a2[rr][2] = a2[rr][3] = 0.0f; }
    for (int e = 0; e < 256; e += 4) {
        float4 q0 = *(const float4*)&fw2[(e + 0) * 256 + d0];
        float4 q1 = *(const float4*)&fw2[(e + 1) * 256 + d0];
        float4 q2 = *(const float4*)&fw2[(e + 2) * 256 + d0];
        float4 q3 = *(const float4*)&fw2[(e + 3) * 256 + d0];
        #pragma unroll
        for (int rr = 0; rr < 2; ++rr) {
            float4 z4 = *(const float4*)&zb[(tr * 2 + rr) * 256 + e];
            a2[rr][0] += z4.x * q0.x + z4.y * q1.x + z4.z * q2.x + z4.w * q3.x;
            a2[rr][1] += z4.x * q0.y + z4.y * q1.y + z4.z * q2.y + z4.w * q3.y;
            a2[rr][2] += z4.x * q0.z + z4.y * q1.z + z4.z * q2.z + z4.w * q3.z;
            a2[rr][3] += z4.x * q0.w + z4.y * q1.w + z4.z * q2.w + z4.w * q3.w;
        }
    }

    float4 b2v = *(const float4*)&fb2[d0];
    float4 mbv = *(const float4*)&meta_b[d0];
    float4 m0v = *(const float4*)&meta_w[0 * 256 + d0];
    float4 m1v = *(const float4*)&meta_w[1 * 256 + d0];
    float4 m2v = *(const float4*)&meta_w[2 * 256 + d0];
    float4 m3v = *(const float4*)&meta_w[3 * 256 + d0];
    #pragma unroll
    for (int rr = 0; rr < 2; ++rr) {
        int r = tr * 2 + rr;
        int n = rb + r;
        float m0 = meta_s[r][0], m1 = meta_s[r][1], m2 = meta_s[r][2], m3 = meta_s[r][3];
        float4 res;
        res.x = a2[rr][0] + b2v.x + mbv.x + m0 * m0v.x + m1 * m1v.x + m2 * m2v.x + m3 * m3v.x;
        res.y = a2[rr][1] + b2v.y + mbv.y + m0 * m0v.y + m1 * m1v.y + m2 * m2v.y + m3 * m3v.y;
        res.z = a2[rr][2] + b2v.z + mbv.z + m0 * m0v.z + m1 * m1v.z + m2 * m2v.z + m3 * m3v.z;
        res.w = a2[rr][3] + b2v.w + mbv.w + m0 * m0v.w + m1 * m1v.w + m2 * m2v.w + m3 * m3v.w;
        *(float4*)&out[n * 256 + d0] = res;
    }
}

extern "C" void kernel_launch(void* const* d_in, const int* in_sizes, int n_in,
                              void* d_out, int out_size, void* d_ws, size_t ws_size,
                              hipStream_t stream) {
    const float* values    = (const float*)d_in[0];
    const int*   kinds     = (const int*)d_in[1];
    const int*   mask      = (const int*)d_in[2];
    const int*   prim_type = (const int*)d_in[3];
    const int*   layer_id  = (const int*)d_in[4];
    const float* meta      = (const float*)d_in[5];
    const float* B_ff      = (const float*)d_in[6];
    const float* kind_emb  = (const float*)d_in[7];
    const float* type_emb  = (const float*)d_in[8];
    const float* layer_emb = (const float*)d_in[9];
    const float* mlp_w1    = (const float*)d_in[10];
    const float* mlp_b1    = (const float*)d_in[11];
    const float* mlp_w2    = (const float*)d_in[12];
    const float* mlp_b2    = (const float*)d_in[13];
    const float* fuse_w1   = (const float*)d_in[14];
    const float* fuse_b1   = (const float*)d_in[15];
    const float* fuse_w2   = (const float*)d_in[16];
    const float* fuse_b2   = (const float*)d_in[17];
    const float* meta_w    = (const float*)d_in[18];
    const float* meta_b    = (const float*)d_in[19];

    short* wsf   = (short*)d_ws;
    float* h_num = (float*)((char*)d_ws + HNUM_OFF);
    float* out   = (float*)d_out;

    prep_kernel<<<160, 512, 0, stream>>>(mlp_w1, mlp_w2, wsf);
    window_kernel<<<NWIN_, 512, 0, stream>>>(values, kinds, mask, B_ff, kind_emb,
                                             mlp_b1, mlp_b2, wsf, h_num);
    fuse_kernel<<<512, 256, 0, stream>>>(h_num, prim_type, layer_id, meta,
                                         type_emb, layer_emb, fuse_w1, fuse_b1,
                                         fuse_w2, fuse_b2, meta_w, meta_b, out);
}